// Round 1
// baseline (4348.261 us; speedup 1.0000x reference)
//
#include <hip/hip_runtime.h>

#define N_NODES 100000
#define N_EDGES 1600000
#define IN_DIM 128
#define HID_DIM 128
#define OUT_DIM 64

// ---------------- degree kernels ----------------

__global__ __launch_bounds__(256) void deg_k(const int* __restrict__ src,
                                             const int* __restrict__ dst,
                                             int* __restrict__ dego,
                                             int* __restrict__ degi) {
    int i = blockIdx.x * 256 + threadIdx.x;
    if (i < N_EDGES) {
        atomicAdd(&dego[src[i]], 1);
        atomicAdd(&degi[dst[i]], 1);
    }
}

__global__ __launch_bounds__(256) void inv_k(const int* __restrict__ dego,
                                             const int* __restrict__ degi,
                                             float* __restrict__ invo,
                                             float* __restrict__ invi) {
    int i = blockIdx.x * 256 + threadIdx.x;
    if (i < N_NODES) {
        invo[i] = 1.0f / sqrtf(fmaxf((float)dego[i], 1.0f));
        invi[i] = 1.0f / sqrtf(fmaxf((float)degi[i], 1.0f));
    }
}

// ---------------- edge scatter (gather src row, scale by inv_out[src], atomic-add into agg[dst]) ----------------

template <int D>
__global__ __launch_bounds__(256) void scatter_k(const float* __restrict__ x,
                                                 const int* __restrict__ src,
                                                 const int* __restrict__ dst,
                                                 const float* __restrict__ sscale,
                                                 float* __restrict__ agg) {
    constexpr int D4 = D / 4;
    long long gid = (long long)blockIdx.x * 256 + threadIdx.x;
    int e = (int)(gid / D4);
    int q = (int)(gid % D4);
    if (e >= N_EDGES) return;
    int s = src[e];
    int d = dst[e];
    float sc = sscale[s];
    float4 v = ((const float4*)x)[(size_t)s * D4 + q];
    float* a = agg + (size_t)d * D + q * 4;
    atomicAdd(a + 0, v.x * sc);
    atomicAdd(a + 1, v.y * sc);
    atomicAdd(a + 2, v.z * sc);
    atomicAdd(a + 3, v.w * sc);
}

// ---------------- small dense GEMM: out[N,BN] = (A[N,128] * rscale?) @ W[128,BN] (+bias) (ReLU?) ----------------
// BM=32 rows per block, 256 threads. W staged fully in LDS, A tile staged (padded stride).

template <int BN, int TR, bool SCALE_IN, bool ADD_BIAS, bool RELU>
__global__ __launch_bounds__(256) void gemm_k(const float* __restrict__ A,
                                              const float* __restrict__ W,
                                              const float* __restrict__ bias,
                                              const float* __restrict__ rscale,
                                              float* __restrict__ out) {
    constexpr int K = 128;
    constexpr int BM = 32;
    constexpr int CG = BN / 8;    // column groups (8 cols each)
    constexpr int RG = 256 / CG;  // row groups; RG*TR == BM
    static_assert(RG * TR == BM, "tile mismatch");

    __shared__ float Ws[K * BN];
    __shared__ float As[BM * (K + 1)];

    int t = threadIdx.x;
    int row0 = blockIdx.x * BM;

    // stage W (float4, coalesced)
    const float4* W4 = (const float4*)W;
    float4* Ws4 = (float4*)Ws;
    #pragma unroll
    for (int i = t; i < K * BN / 4; i += 256) Ws4[i] = W4[i];

    // stage A tile with optional per-row scale; padded row stride K+1
    for (int i = t; i < BM * K / 4; i += 256) {
        int r = i >> 5;   // K/4 == 32 float4 per row
        int c = i & 31;
        float4 v = ((const float4*)(A + (size_t)(row0 + r) * K))[c];
        float s = SCALE_IN ? rscale[row0 + r] : 1.0f;
        float* dp = &As[r * (K + 1) + c * 4];
        dp[0] = v.x * s;
        dp[1] = v.y * s;
        dp[2] = v.z * s;
        dp[3] = v.w * s;
    }
    __syncthreads();

    int cg = t % CG;
    int rg = t / CG;

    float acc[TR][8];
    #pragma unroll
    for (int i = 0; i < TR; ++i)
        #pragma unroll
        for (int j = 0; j < 8; ++j) acc[i][j] = 0.0f;

    #pragma unroll 8
    for (int k = 0; k < K; ++k) {
        float4 w0 = *(const float4*)&Ws[k * BN + cg * 8];
        float4 w1 = *(const float4*)&Ws[k * BN + cg * 8 + 4];
        #pragma unroll
        for (int i = 0; i < TR; ++i) {
            float a = As[(rg * TR + i) * (K + 1) + k];
            acc[i][0] += a * w0.x;
            acc[i][1] += a * w0.y;
            acc[i][2] += a * w0.z;
            acc[i][3] += a * w0.w;
            acc[i][4] += a * w1.x;
            acc[i][5] += a * w1.y;
            acc[i][6] += a * w1.z;
            acc[i][7] += a * w1.w;
        }
    }

    #pragma unroll
    for (int i = 0; i < TR; ++i) {
        int row = row0 + rg * TR + i;
        float v[8];
        #pragma unroll
        for (int j = 0; j < 8; ++j) {
            float x = acc[i][j];
            if (ADD_BIAS) x += bias[cg * 8 + j];
            if (RELU) x = fmaxf(x, 0.0f);
            v[j] = x;
        }
        float4* op = (float4*)(out + (size_t)row * BN + cg * 8);
        op[0] = make_float4(v[0], v[1], v[2], v[3]);
        op[1] = make_float4(v[4], v[5], v[6], v[7]);
    }
}

// ---------------- epilogue: out = agg2 * inv_in[row] + b2 ----------------

__global__ __launch_bounds__(256) void final_k(const float* __restrict__ agg2,
                                               const float* __restrict__ invi,
                                               const float* __restrict__ b2,
                                               float* __restrict__ out) {
    int gid = blockIdx.x * 256 + threadIdx.x;  // one float4 per thread
    if (gid >= N_NODES * (OUT_DIM / 4)) return;
    int row = gid >> 4;  // OUT_DIM/4 == 16
    int q = gid & 15;
    float s = invi[row];
    float4 v = ((const float4*)agg2)[gid];
    float4 b = ((const float4*)b2)[q];
    ((float4*)out)[gid] = make_float4(v.x * s + b.x, v.y * s + b.y, v.z * s + b.z, v.w * s + b.w);
}

extern "C" void kernel_launch(void* const* d_in, const int* in_sizes, int n_in,
                              void* d_out, int out_size, void* d_ws, size_t ws_size,
                              hipStream_t stream) {
    const float* in_feat = (const float*)d_in[0];
    const float* W1 = (const float*)d_in[1];
    const float* b1 = (const float*)d_in[2];
    const float* W2 = (const float*)d_in[3];
    const float* b2 = (const float*)d_in[4];
    const int* src = (const int*)d_in[5];
    const int* dst = (const int*)d_in[6];
    float* out = (float*)d_out;

    // workspace layout (all 16B-aligned)
    char* w = (char*)d_ws;
    int* dego = (int*)w;      w += (size_t)N_NODES * 4;
    int* degi = (int*)w;      w += (size_t)N_NODES * 4;
    float* invo = (float*)w;  w += (size_t)N_NODES * 4;
    float* invi = (float*)w;  w += (size_t)N_NODES * 4;
    float* agg1 = (float*)w;  w += (size_t)N_NODES * HID_DIM * 4;
    float* h = (float*)w;     w += (size_t)N_NODES * HID_DIM * 4;
    float* y = agg1;                                   // reuse: agg1 dead after gemm1
    float* agg2 = agg1 + (size_t)N_NODES * OUT_DIM;    // second half of agg1 region

    // degrees + inverse sqrt
    hipMemsetAsync(dego, 0, (size_t)N_NODES * 8, stream);  // dego + degi contiguous
    deg_k<<<(N_EDGES + 255) / 256, 256, 0, stream>>>(src, dst, dego, degi);
    inv_k<<<(N_NODES + 255) / 256, 256, 0, stream>>>(dego, degi, invo, invi);

    // layer 1: agg1[dst] += in_feat[src] * inv_out[src];  h = relu((agg1*inv_in)@W1 + b1)
    hipMemsetAsync(agg1, 0, (size_t)N_NODES * HID_DIM * 4, stream);
    scatter_k<IN_DIM><<<N_EDGES * (IN_DIM / 4) / 256, 256, 0, stream>>>(in_feat, src, dst, invo, agg1);
    gemm_k<HID_DIM, 2, true, true, true><<<N_NODES / 32, 256, 0, stream>>>(agg1, W1, b1, invi, h);

    // layer 2 (W applied before aggregation — linearity): y = h@W2; agg2[dst] += y[src]*inv_out[src];
    // out = agg2*inv_in + b2
    gemm_k<OUT_DIM, 1, false, false, false><<<N_NODES / 32, 256, 0, stream>>>(h, W2, nullptr, nullptr, y);
    hipMemsetAsync(agg2, 0, (size_t)N_NODES * OUT_DIM * 4, stream);
    scatter_k<OUT_DIM><<<N_EDGES * (OUT_DIM / 4) / 256, 256, 0, stream>>>(y, src, dst, invo, agg2);
    final_k<<<(N_NODES * (OUT_DIM / 4) + 255) / 256, 256, 0, stream>>>(agg2, invi, b2, out);
}

// Round 2
// 693.351 us; speedup vs baseline: 6.2714x; 6.2714x over previous
//
#include <hip/hip_runtime.h>

#define N_NODES 100000
#define N_EDGES 1600000
#define IN_DIM 128
#define HID_DIM 128
#define OUT_DIM 64
#define NBLK ((N_NODES + 255) / 256)  // 391

// ---------------- degrees ----------------

__global__ __launch_bounds__(256) void deg_k(const int* __restrict__ src,
                                             const int* __restrict__ dst,
                                             int* __restrict__ dego,
                                             int* __restrict__ degi) {
    int i = blockIdx.x * 256 + threadIdx.x;
    if (i < N_EDGES) {
        atomicAdd(&dego[src[i]], 1);
        atomicAdd(&degi[dst[i]], 1);
    }
}

__global__ __launch_bounds__(256) void inv_k(const int* __restrict__ dego,
                                             const int* __restrict__ degi,
                                             float* __restrict__ invo,
                                             float* __restrict__ invi) {
    int i = blockIdx.x * 256 + threadIdx.x;
    if (i < N_NODES) {
        invo[i] = rsqrtf(fmaxf((float)dego[i], 1.0f));
        invi[i] = rsqrtf(fmaxf((float)degi[i], 1.0f));
    }
}

// ---------------- exclusive prefix scan of degi -> ofs (3 kernels) ----------------

__global__ __launch_bounds__(256) void scan_part_k(const int* __restrict__ degi,
                                                   int* __restrict__ partial) {
    __shared__ int s[256];
    int t = threadIdx.x;
    int i = blockIdx.x * 256 + t;
    s[t] = (i < N_NODES) ? degi[i] : 0;
    __syncthreads();
    for (int off = 128; off > 0; off >>= 1) {
        if (t < off) s[t] += s[t + off];
        __syncthreads();
    }
    if (t == 0) partial[blockIdx.x] = s[0];
}

__global__ __launch_bounds__(512) void scan_top_k(const int* __restrict__ partial,
                                                  int* __restrict__ partofs) {
    __shared__ int s[512];
    int t = threadIdx.x;
    int v = (t < NBLK) ? partial[t] : 0;
    s[t] = v;
    __syncthreads();
    for (int off = 1; off < 512; off <<= 1) {
        int x = (t >= off) ? s[t - off] : 0;
        __syncthreads();
        s[t] += x;
        __syncthreads();
    }
    if (t < NBLK) partofs[t] = s[t] - v;  // exclusive
}

__global__ __launch_bounds__(256) void scan_final_k(const int* __restrict__ degi,
                                                    const int* __restrict__ partofs,
                                                    int* __restrict__ ofs,
                                                    int* __restrict__ fill) {
    __shared__ int s[256];
    int t = threadIdx.x;
    int i = blockIdx.x * 256 + t;
    int v = (i < N_NODES) ? degi[i] : 0;
    s[t] = v;
    __syncthreads();
    for (int off = 1; off < 256; off <<= 1) {
        int x = (t >= off) ? s[t - off] : 0;
        __syncthreads();
        s[t] += x;
        __syncthreads();
    }
    if (i < N_NODES) {
        int e = partofs[blockIdx.x] + s[t] - v;
        ofs[i] = e;
        fill[i] = e;
    }
    if (i == 0) ofs[N_NODES] = N_EDGES;
}

// ---------------- bin edges by dst (CSR) ----------------

__global__ __launch_bounds__(256) void bin_k(const int* __restrict__ src,
                                             const int* __restrict__ dst,
                                             int* __restrict__ fill,
                                             int* __restrict__ esrc) {
    int e = blockIdx.x * 256 + threadIdx.x;
    if (e < N_EDGES) {
        int pos = atomicAdd(&fill[dst[e]], 1);
        esrc[pos] = src[e];
    }
}

// ---------------- xs = x * invo[row] ----------------

__global__ __launch_bounds__(256) void scale_rows_k(const float* __restrict__ x,
                                                    const float* __restrict__ invo,
                                                    float* __restrict__ xs) {
    int gid = blockIdx.x * 256 + threadIdx.x;  // float4 units; grid exact
    int row = gid >> 5;                        // IN_DIM/4 == 32
    float s = invo[row];
    float4 v = ((const float4*)x)[gid];
    ((float4*)xs)[gid] = make_float4(v.x * s, v.y * s, v.z * s, v.w * s);
}

// ---------------- CSR aggregation: one wave per node, register accumulation ----------------

__global__ __launch_bounds__(256) void agg128_k(const float* __restrict__ xs,
                                                const int* __restrict__ esrc,
                                                const int* __restrict__ ofs,
                                                const float* __restrict__ invi,
                                                float* __restrict__ a) {
    int wid = (blockIdx.x * 256 + threadIdx.x) >> 6;
    int lane = threadIdx.x & 63;
    if (wid >= N_NODES) return;
    int beg = ofs[wid], end = ofs[wid + 1];
    float ax = 0.f, ay = 0.f;
    const float2* x2 = (const float2*)xs;
    for (int j = beg; j < end; j += 64) {
        int m = end - j;
        if (m > 64) m = 64;
        int idx = (lane < m) ? esrc[j + lane] : 0;
        for (int t = 0; t < m; ++t) {
            int s = __shfl(idx, t);
            float2 v = x2[s * 64 + lane];
            ax += v.x;
            ay += v.y;
        }
    }
    float sc = invi[wid];
    ((float2*)a)[wid * 64 + lane] = make_float2(ax * sc, ay * sc);
}

__global__ __launch_bounds__(256) void agg64_k(const float* __restrict__ ys,
                                               const int* __restrict__ esrc,
                                               const int* __restrict__ ofs,
                                               const float* __restrict__ invi,
                                               const float* __restrict__ b2,
                                               float* __restrict__ out) {
    int wid = (blockIdx.x * 256 + threadIdx.x) >> 6;
    int lane = threadIdx.x & 63;
    if (wid >= N_NODES) return;
    int beg = ofs[wid], end = ofs[wid + 1];
    float acc = 0.f;
    for (int j = beg; j < end; j += 64) {
        int m = end - j;
        if (m > 64) m = 64;
        int idx = (lane < m) ? esrc[j + lane] : 0;
        for (int t = 0; t < m; ++t) {
            int s = __shfl(idx, t);
            acc += ys[s * 64 + lane];
        }
    }
    out[wid * 64 + lane] = acc * invi[wid] + b2[lane];
}

// ---------------- dense GEMM: out[N,BN] = A[N,128] @ W[128,BN] (+bias)(relu)(*oscale[row]) ----------------

template <int BN, int TR, bool ADD_BIAS, bool RELU, bool SCALE_OUT>
__global__ __launch_bounds__(256) void gemm_k(const float* __restrict__ A,
                                              const float* __restrict__ W,
                                              const float* __restrict__ bias,
                                              const float* __restrict__ oscale,
                                              float* __restrict__ out) {
    constexpr int K = 128;
    constexpr int BM = 32;
    constexpr int CG = BN / 8;    // column groups (8 cols each)
    constexpr int RG = 256 / CG;  // row groups; RG*TR == BM
    static_assert(RG * TR == BM, "tile mismatch");

    __shared__ float Ws[K * BN];
    __shared__ float As[BM * (K + 1)];

    int t = threadIdx.x;
    int row0 = blockIdx.x * BM;

    const float4* W4 = (const float4*)W;
    float4* Ws4 = (float4*)Ws;
    #pragma unroll
    for (int i = t; i < K * BN / 4; i += 256) Ws4[i] = W4[i];

    for (int i = t; i < BM * K / 4; i += 256) {
        int r = i >> 5;  // K/4 == 32 float4 per row
        int c = i & 31;
        float4 v = ((const float4*)(A + (size_t)(row0 + r) * K))[c];
        float* dp = &As[r * (K + 1) + c * 4];
        dp[0] = v.x; dp[1] = v.y; dp[2] = v.z; dp[3] = v.w;
    }
    __syncthreads();

    int cg = t % CG;
    int rg = t / CG;

    float acc[TR][8];
    #pragma unroll
    for (int i = 0; i < TR; ++i)
        #pragma unroll
        for (int j = 0; j < 8; ++j) acc[i][j] = 0.0f;

    #pragma unroll 8
    for (int k = 0; k < K; ++k) {
        float4 w0 = *(const float4*)&Ws[k * BN + cg * 8];
        float4 w1 = *(const float4*)&Ws[k * BN + cg * 8 + 4];
        #pragma unroll
        for (int i = 0; i < TR; ++i) {
            float a = As[(rg * TR + i) * (K + 1) + k];
            acc[i][0] += a * w0.x;
            acc[i][1] += a * w0.y;
            acc[i][2] += a * w0.z;
            acc[i][3] += a * w0.w;
            acc[i][4] += a * w1.x;
            acc[i][5] += a * w1.y;
            acc[i][6] += a * w1.z;
            acc[i][7] += a * w1.w;
        }
    }

    #pragma unroll
    for (int i = 0; i < TR; ++i) {
        int row = row0 + rg * TR + i;
        float os = SCALE_OUT ? oscale[row] : 1.0f;
        float v[8];
        #pragma unroll
        for (int j = 0; j < 8; ++j) {
            float x = acc[i][j];
            if (ADD_BIAS) x += bias[cg * 8 + j];
            if (RELU) x = fmaxf(x, 0.0f);
            if (SCALE_OUT) x *= os;
            v[j] = x;
        }
        float4* op = (float4*)(out + (size_t)row * BN + cg * 8);
        op[0] = make_float4(v[0], v[1], v[2], v[3]);
        op[1] = make_float4(v[4], v[5], v[6], v[7]);
    }
}

extern "C" void kernel_launch(void* const* d_in, const int* in_sizes, int n_in,
                              void* d_out, int out_size, void* d_ws, size_t ws_size,
                              hipStream_t stream) {
    const float* in_feat = (const float*)d_in[0];
    const float* W1 = (const float*)d_in[1];
    const float* b1 = (const float*)d_in[2];
    const float* W2 = (const float*)d_in[3];
    const float* b2 = (const float*)d_in[4];
    const int* src = (const int*)d_in[5];
    const int* dst = (const int*)d_in[6];
    float* out = (float*)d_out;

    // workspace layout (16B aligned slots)
    char* w = (char*)d_ws;
    int* dego = (int*)w;      w += (size_t)N_NODES * 4;      // dego+degi contiguous for one memset
    int* degi = (int*)w;      w += (size_t)N_NODES * 4;
    float* invo = (float*)w;  w += (size_t)N_NODES * 4;
    float* invi = (float*)w;  w += (size_t)N_NODES * 4;
    int* ofs = (int*)w;       w += (size_t)(N_NODES + 4) * 4;
    int* fill = (int*)w;      w += (size_t)N_NODES * 4;
    int* partial = (int*)w;   w += (size_t)((NBLK + 3) / 4) * 16;
    int* partofs = (int*)w;   w += (size_t)((NBLK + 3) / 4) * 16;
    int* esrc = (int*)w;      w += (size_t)N_EDGES * 4;
    float* bufA = (float*)w;  w += (size_t)N_NODES * HID_DIM * 4;  // xs, then h
    float* bufB = (float*)w;  w += (size_t)N_NODES * HID_DIM * 4;  // a, then ys

    // degrees + norms
    hipMemsetAsync(dego, 0, (size_t)N_NODES * 8, stream);
    deg_k<<<(N_EDGES + 255) / 256, 256, 0, stream>>>(src, dst, dego, degi);
    inv_k<<<NBLK, 256, 0, stream>>>(dego, degi, invo, invi);

    // CSR build (by dst)
    scan_part_k<<<NBLK, 256, 0, stream>>>(degi, partial);
    scan_top_k<<<1, 512, 0, stream>>>(partial, partofs);
    scan_final_k<<<NBLK, 256, 0, stream>>>(degi, partofs, ofs, fill);
    bin_k<<<(N_EDGES + 255) / 256, 256, 0, stream>>>(src, dst, fill, esrc);

    // layer 1: xs = x*invo; a = invi * Agg(xs); h = relu(a@W1 + b1)
    scale_rows_k<<<N_NODES * (IN_DIM / 4) / 256, 256, 0, stream>>>(in_feat, invo, bufA);
    agg128_k<<<N_NODES / 4, 256, 0, stream>>>(bufA, esrc, ofs, invi, bufB);
    gemm_k<HID_DIM, 2, true, true, false><<<N_NODES / 32, 256, 0, stream>>>(bufB, W1, b1, nullptr, bufA);

    // layer 2: ys = (h@W2)*invo; out = invi * Agg(ys) + b2
    gemm_k<OUT_DIM, 1, false, false, true><<<N_NODES / 32, 256, 0, stream>>>(bufA, W2, nullptr, invo, bufB);
    agg64_k<<<N_NODES / 4, 256, 0, stream>>>(bufB, esrc, ofs, invi, b2, out);
}

// Round 3
// 523.337 us; speedup vs baseline: 8.3087x; 1.3249x over previous
//
#include <hip/hip_runtime.h>

#define N_NODES 100000
#define N_EDGES 1600000
#define IN_DIM 128
#define HID_DIM 128
#define OUT_DIM 64
#define NBLK ((N_NODES + 255) / 256)  // 391

typedef unsigned short ushort_t;
typedef unsigned int uint_t;

// bf16 helpers (manual, RNE pack / shift unpack)
__device__ __forceinline__ float blo(uint_t u) { return __uint_as_float(u << 16); }
__device__ __forceinline__ float bhi(uint_t u) { return __uint_as_float(u & 0xFFFF0000u); }
__device__ __forceinline__ uint_t f2b(float f) {
    uint_t u = __float_as_uint(f);
    uint_t r = u + 0x7FFFu + ((u >> 16) & 1u);
    return r >> 16;
}
__device__ __forceinline__ uint_t pk2(float a, float b) { return f2b(a) | (f2b(b) << 16); }

// ---------------- degrees ----------------

__global__ __launch_bounds__(256) void deg_k(const int* __restrict__ src,
                                             const int* __restrict__ dst,
                                             int* __restrict__ dego,
                                             int* __restrict__ degi) {
    int i = blockIdx.x * 256 + threadIdx.x;
    if (i < N_EDGES) {
        atomicAdd(&dego[src[i]], 1);
        atomicAdd(&degi[dst[i]], 1);
    }
}

__global__ __launch_bounds__(256) void inv_k(const int* __restrict__ dego,
                                             const int* __restrict__ degi,
                                             float* __restrict__ invo,
                                             float* __restrict__ invi) {
    int i = blockIdx.x * 256 + threadIdx.x;
    if (i < N_NODES) {
        invo[i] = rsqrtf(fmaxf((float)dego[i], 1.0f));
        invi[i] = rsqrtf(fmaxf((float)degi[i], 1.0f));
    }
}

// ---------------- exclusive prefix scan of degi -> ofs ----------------

__global__ __launch_bounds__(256) void scan_part_k(const int* __restrict__ degi,
                                                   int* __restrict__ partial) {
    __shared__ int s[256];
    int t = threadIdx.x;
    int i = blockIdx.x * 256 + t;
    s[t] = (i < N_NODES) ? degi[i] : 0;
    __syncthreads();
    for (int off = 128; off > 0; off >>= 1) {
        if (t < off) s[t] += s[t + off];
        __syncthreads();
    }
    if (t == 0) partial[blockIdx.x] = s[0];
}

__global__ __launch_bounds__(512) void scan_top_k(const int* __restrict__ partial,
                                                  int* __restrict__ partofs) {
    __shared__ int s[512];
    int t = threadIdx.x;
    int v = (t < NBLK) ? partial[t] : 0;
    s[t] = v;
    __syncthreads();
    for (int off = 1; off < 512; off <<= 1) {
        int x = (t >= off) ? s[t - off] : 0;
        __syncthreads();
        s[t] += x;
        __syncthreads();
    }
    if (t < NBLK) partofs[t] = s[t] - v;  // exclusive
}

__global__ __launch_bounds__(256) void scan_final_k(const int* __restrict__ degi,
                                                    const int* __restrict__ partofs,
                                                    int* __restrict__ ofs,
                                                    int* __restrict__ fill) {
    __shared__ int s[256];
    int t = threadIdx.x;
    int i = blockIdx.x * 256 + t;
    int v = (i < N_NODES) ? degi[i] : 0;
    s[t] = v;
    __syncthreads();
    for (int off = 1; off < 256; off <<= 1) {
        int x = (t >= off) ? s[t - off] : 0;
        __syncthreads();
        s[t] += x;
        __syncthreads();
    }
    if (i < N_NODES) {
        int e = partofs[blockIdx.x] + s[t] - v;
        ofs[i] = e;
        fill[i] = e;
    }
    if (i == 0) ofs[N_NODES] = N_EDGES;
}

__global__ __launch_bounds__(256) void bin_k(const int* __restrict__ src,
                                             const int* __restrict__ dst,
                                             int* __restrict__ fill,
                                             int* __restrict__ esrc) {
    int e = blockIdx.x * 256 + threadIdx.x;
    if (e < N_EDGES) {
        int pos = atomicAdd(&fill[dst[e]], 1);
        esrc[pos] = src[e];
    }
}

// ---------------- prep: xs_bf16 = in_feat * invo[row] ----------------

__global__ __launch_bounds__(256) void prep_k(const float* __restrict__ x,
                                              const float* __restrict__ invo,
                                              ushort_t* __restrict__ xs) {
    int gid = blockIdx.x * 256 + threadIdx.x;  // one uint4 (8 elems); grid exact
    int row = gid >> 4;                        // 128/8 == 16 chunks per row
    float s = invo[row];
    const float4* xp = (const float4*)x + (size_t)gid * 2;
    float4 va = xp[0], vb = xp[1];
    ((uint4*)xs)[gid] = make_uint4(pk2(va.x * s, va.y * s), pk2(va.z * s, va.w * s),
                                   pk2(vb.x * s, vb.y * s), pk2(vb.z * s, vb.w * s));
}

// ---------------- agg over 128-dim bf16 rows: one wave/node, quarter-wave per edge ----------------
// lane = q*16+li; lane li covers cols 8li..8li+7; 4 edges in flight per iteration.

__global__ __launch_bounds__(256) void agg128_k(const ushort_t* __restrict__ xs,
                                                const int* __restrict__ esrc,
                                                const int* __restrict__ ofs,
                                                const float* __restrict__ invi,
                                                ushort_t* __restrict__ a) {
    int wid = (blockIdx.x * 256 + threadIdx.x) >> 6;
    int lane = threadIdx.x & 63;
    if (wid >= N_NODES) return;
    int q = lane >> 4, li = lane & 15;
    int beg = ofs[wid], end = ofs[wid + 1];
    float acc[8];
    #pragma unroll
    for (int i = 0; i < 8; ++i) acc[i] = 0.f;

    for (int j = beg; j < end; j += 64) {
        int m = end - j;
        if (m > 64) m = 64;
        int idx = (lane < m) ? esrc[j + lane] : 0;
        for (int t = 0; 4 * t < m; ++t) {
            int e = 4 * t + q;
            int s = __shfl(idx, e);
            if (e < m) {
                uint4 v = *(const uint4*)(xs + (size_t)s * 128 + li * 8);
                acc[0] += blo(v.x); acc[1] += bhi(v.x);
                acc[2] += blo(v.y); acc[3] += bhi(v.y);
                acc[4] += blo(v.z); acc[5] += bhi(v.z);
                acc[6] += blo(v.w); acc[7] += bhi(v.w);
            }
        }
    }
    #pragma unroll
    for (int i = 0; i < 8; ++i) acc[i] += __shfl(acc[i], lane ^ 16);
    #pragma unroll
    for (int i = 0; i < 8; ++i) acc[i] += __shfl(acc[i], lane ^ 32);

    if (lane < 16) {
        float sc = invi[wid];
        *(uint4*)(a + (size_t)wid * 128 + li * 8) =
            make_uint4(pk2(acc[0] * sc, acc[1] * sc), pk2(acc[2] * sc, acc[3] * sc),
                       pk2(acc[4] * sc, acc[5] * sc), pk2(acc[6] * sc, acc[7] * sc));
    }
}

// ---------------- agg over 64-dim bf16 rows + bias -> f32 out ----------------

__global__ __launch_bounds__(256) void agg64_k(const ushort_t* __restrict__ ys,
                                               const int* __restrict__ esrc,
                                               const int* __restrict__ ofs,
                                               const float* __restrict__ invi,
                                               const float* __restrict__ b2,
                                               float* __restrict__ out) {
    int wid = (blockIdx.x * 256 + threadIdx.x) >> 6;
    int lane = threadIdx.x & 63;
    if (wid >= N_NODES) return;
    int q = lane >> 4, li = lane & 15;
    int beg = ofs[wid], end = ofs[wid + 1];
    float acc[4];
    #pragma unroll
    for (int i = 0; i < 4; ++i) acc[i] = 0.f;

    for (int j = beg; j < end; j += 64) {
        int m = end - j;
        if (m > 64) m = 64;
        int idx = (lane < m) ? esrc[j + lane] : 0;
        for (int t = 0; 4 * t < m; ++t) {
            int e = 4 * t + q;
            int s = __shfl(idx, e);
            if (e < m) {
                uint2 v = *(const uint2*)(ys + (size_t)s * 64 + li * 4);
                acc[0] += blo(v.x); acc[1] += bhi(v.x);
                acc[2] += blo(v.y); acc[3] += bhi(v.y);
            }
        }
    }
    #pragma unroll
    for (int i = 0; i < 4; ++i) acc[i] += __shfl(acc[i], lane ^ 16);
    #pragma unroll
    for (int i = 0; i < 4; ++i) acc[i] += __shfl(acc[i], lane ^ 32);

    if (lane < 16) {
        float sc = invi[wid];
        float4 b = *(const float4*)(b2 + li * 4);
        *(float4*)(out + (size_t)wid * 64 + li * 4) =
            make_float4(acc[0] * sc + b.x, acc[1] * sc + b.y,
                        acc[2] * sc + b.z, acc[3] * sc + b.w);
    }
}

// ---------------- GEMM: out_bf16[N,BN] = A_bf16[N,128] @ W_f32[128,BN] (+bias)(relu)(*oscale) ----------------
// Split-column assignment (j0 = cg*4, j1 = BN/2 + cg*4) keeps LDS reads conflict-free.

template <int BN, int TR, bool ADD_BIAS, bool RELU, bool SCALE_OUT>
__global__ __launch_bounds__(256) void gemm_k(const ushort_t* __restrict__ A,
                                              const float* __restrict__ W,
                                              const float* __restrict__ bias,
                                              const float* __restrict__ oscale,
                                              ushort_t* __restrict__ out) {
    constexpr int K = 128;
    constexpr int BM = 32;
    constexpr int CG = BN / 8;
    constexpr int RG = 256 / CG;
    static_assert(RG * TR == BM, "tile mismatch");

    __shared__ ushort_t Wsb[K * BN];      // bf16
    __shared__ float As[BM * (K + 1)];

    int t = threadIdx.x;
    int row0 = blockIdx.x * BM;

    // stage W (f32 global -> bf16 LDS)
    for (int i = t; i < K * BN / 4; i += 256) {
        float4 v = ((const float4*)W)[i];
        ((uint2*)Wsb)[i] = make_uint2(pk2(v.x, v.y), pk2(v.z, v.w));
    }
    // stage A (bf16 global -> f32 LDS, padded stride K+1)
    for (int i = t; i < BM * K / 8; i += 256) {
        int r = i >> 4;  // 16 uint4-chunks per row
        int c = i & 15;
        uint4 v = ((const uint4*)(A + (size_t)(row0 + r) * K))[c];
        float* dp = &As[r * (K + 1) + c * 8];
        dp[0] = blo(v.x); dp[1] = bhi(v.x);
        dp[2] = blo(v.y); dp[3] = bhi(v.y);
        dp[4] = blo(v.z); dp[5] = bhi(v.z);
        dp[6] = blo(v.w); dp[7] = bhi(v.w);
    }
    __syncthreads();

    int cg = t % CG, rg = t / CG;
    int j0 = cg * 4, j1 = BN / 2 + cg * 4;

    float acc[TR][8];
    #pragma unroll
    for (int i = 0; i < TR; ++i)
        #pragma unroll
        for (int j = 0; j < 8; ++j) acc[i][j] = 0.0f;

    #pragma unroll 4
    for (int k = 0; k < K; ++k) {
        uint2 wa = *(const uint2*)&Wsb[k * BN + j0];
        uint2 wb = *(const uint2*)&Wsb[k * BN + j1];
        float wv[8];
        wv[0] = blo(wa.x); wv[1] = bhi(wa.x); wv[2] = blo(wa.y); wv[3] = bhi(wa.y);
        wv[4] = blo(wb.x); wv[5] = bhi(wb.x); wv[6] = blo(wb.y); wv[7] = bhi(wb.y);
        #pragma unroll
        for (int i = 0; i < TR; ++i) {
            float a = As[(rg * TR + i) * (K + 1) + k];
            #pragma unroll
            for (int j = 0; j < 8; ++j) acc[i][j] += a * wv[j];
        }
    }

    #pragma unroll
    for (int i = 0; i < TR; ++i) {
        int row = row0 + rg * TR + i;
        float os = SCALE_OUT ? oscale[row] : 1.0f;
        float v[8];
        #pragma unroll
        for (int j = 0; j < 8; ++j) {
            float x = acc[i][j];
            if (ADD_BIAS) x += bias[(j < 4) ? (j0 + j) : (j1 + j - 4)];
            if (RELU) x = fmaxf(x, 0.0f);
            if (SCALE_OUT) x *= os;
            v[j] = x;
        }
        ushort_t* op = out + (size_t)row * BN;
        *(uint2*)(op + j0) = make_uint2(pk2(v[0], v[1]), pk2(v[2], v[3]));
        *(uint2*)(op + j1) = make_uint2(pk2(v[4], v[5]), pk2(v[6], v[7]));
    }
}

extern "C" void kernel_launch(void* const* d_in, const int* in_sizes, int n_in,
                              void* d_out, int out_size, void* d_ws, size_t ws_size,
                              hipStream_t stream) {
    const float* in_feat = (const float*)d_in[0];
    const float* W1 = (const float*)d_in[1];
    const float* b1 = (const float*)d_in[2];
    const float* W2 = (const float*)d_in[3];
    const float* b2 = (const float*)d_in[4];
    const int* src = (const int*)d_in[5];
    const int* dst = (const int*)d_in[6];
    float* out = (float*)d_out;

    // workspace layout
    char* w = (char*)d_ws;
    int* dego = (int*)w;        w += (size_t)N_NODES * 4;  // dego+degi contiguous for one memset
    int* degi = (int*)w;        w += (size_t)N_NODES * 4;
    float* invo = (float*)w;    w += (size_t)N_NODES * 4;
    float* invi = (float*)w;    w += (size_t)N_NODES * 4;
    int* ofs = (int*)w;         w += (size_t)(N_NODES + 4) * 4;
    int* fill = (int*)w;        w += (size_t)N_NODES * 4;
    int* partial = (int*)w;     w += (size_t)((NBLK + 3) / 4) * 16;
    int* partofs = (int*)w;     w += (size_t)((NBLK + 3) / 4) * 16;
    int* esrc = (int*)w;        w += (size_t)N_EDGES * 4;
    ushort_t* bufA = (ushort_t*)w;  w += (size_t)N_NODES * HID_DIM * 2;  // xs -> h
    ushort_t* bufB = (ushort_t*)w;  w += (size_t)N_NODES * HID_DIM * 2;  // a -> ys

    // degrees + norms
    hipMemsetAsync(dego, 0, (size_t)N_NODES * 8, stream);
    deg_k<<<(N_EDGES + 255) / 256, 256, 0, stream>>>(src, dst, dego, degi);
    inv_k<<<NBLK, 256, 0, stream>>>(dego, degi, invo, invi);

    // CSR build (by dst)
    scan_part_k<<<NBLK, 256, 0, stream>>>(degi, partial);
    scan_top_k<<<1, 512, 0, stream>>>(partial, partofs);
    scan_final_k<<<NBLK, 256, 0, stream>>>(degi, partofs, ofs, fill);
    bin_k<<<(N_EDGES + 255) / 256, 256, 0, stream>>>(src, dst, fill, esrc);

    // layer 1: xs = bf16(x*invo); a = bf16(invi*Agg(xs)); h = bf16(relu(a@W1+b1))
    prep_k<<<N_NODES * 16 / 256, 256, 0, stream>>>(in_feat, invo, bufA);
    agg128_k<<<N_NODES / 4, 256, 0, stream>>>(bufA, esrc, ofs, invi, bufB);
    gemm_k<HID_DIM, 2, true, true, false><<<N_NODES / 32, 256, 0, stream>>>(bufB, W1, b1, nullptr, bufA);

    // layer 2: ys = bf16((h@W2)*invo); out = invi*Agg(ys) + b2
    gemm_k<OUT_DIM, 1, false, false, true><<<N_NODES / 32, 256, 0, stream>>>(bufA, W2, nullptr, invo, bufB);
    agg64_k<<<N_NODES / 4, 256, 0, stream>>>(bufB, esrc, ofs, invi, b2, out);
}

// Round 4
// 382.385 us; speedup vs baseline: 11.3714x; 1.3686x over previous
//
#include <hip/hip_runtime.h>

#define N_NODES 100000
#define N_EDGES 1600000
#define IN_DIM 128
#define HID_DIM 128
#define OUT_DIM 64

// ---- bucketed CSR sort geometry ----
#define NB 391                      // buckets: dst>>8, ceil(100000/256)
#define GRIDB 256                   // blocks in hist/scat passes
#define EPB (N_EDGES / GRIDB)       // 6250 edges per block (exact)
#define CELLS (NB * GRIDB)          // 100096 (exact multiple of 256)
#define SNPART (CELLS / 256)        // 391 scan partials

typedef unsigned short ushort_t;
typedef unsigned int uint_t;

// bf16 helpers (manual, RNE pack / shift unpack)
__device__ __forceinline__ float blo(uint_t u) { return __uint_as_float(u << 16); }
__device__ __forceinline__ float bhi(uint_t u) { return __uint_as_float(u & 0xFFFF0000u); }
__device__ __forceinline__ uint_t f2b(float f) {
    uint_t u = __float_as_uint(f);
    uint_t r = u + 0x7FFFu + ((u >> 16) & 1u);
    return r >> 16;
}
__device__ __forceinline__ uint_t pk2(float a, float b) { return f2b(a) | (f2b(b) << 16); }

// ---------------- out-degrees (src side) ----------------

__global__ __launch_bounds__(256) void deg_k(const int* __restrict__ src,
                                             int* __restrict__ dego) {
    int i = blockIdx.x * 256 + threadIdx.x;
    if (i < N_EDGES) atomicAdd(&dego[src[i]], 1);
}

// ---------------- pass A: per-block bucket histogram (LDS atomics only) ----------------

__global__ __launch_bounds__(256) void hist_k(const int* __restrict__ dst,
                                              int* __restrict__ hist) {
    __shared__ int h[NB];
    int t = threadIdx.x, blk = blockIdx.x;
    for (int j = t; j < NB; j += 256) h[j] = 0;
    __syncthreads();
    int e0 = blk * EPB;
    for (int i = e0 + t; i < e0 + EPB; i += 256) atomicAdd(&h[dst[i] >> 8], 1);
    __syncthreads();
    for (int j = t; j < NB; j += 256) hist[j * GRIDB + blk] = h[j];  // bucket-major
}

// ---------------- flat exclusive scan over CELLS ints ----------------

__global__ __launch_bounds__(256) void scan_part_k(const int* __restrict__ in,
                                                   int* __restrict__ partial, int L) {
    __shared__ int s[256];
    int t = threadIdx.x, i = blockIdx.x * 256 + t;
    s[t] = (i < L) ? in[i] : 0;
    __syncthreads();
    for (int off = 128; off > 0; off >>= 1) {
        if (t < off) s[t] += s[t + off];
        __syncthreads();
    }
    if (t == 0) partial[blockIdx.x] = s[0];
}

__global__ __launch_bounds__(512) void scan_top_k(const int* __restrict__ partial,
                                                  int* __restrict__ partofs, int n) {
    __shared__ int s[512];
    int t = threadIdx.x;
    int v = (t < n) ? partial[t] : 0;
    s[t] = v;
    __syncthreads();
    for (int off = 1; off < 512; off <<= 1) {
        int x = (t >= off) ? s[t - off] : 0;
        __syncthreads();
        s[t] += x;
        __syncthreads();
    }
    if (t < n) partofs[t] = s[t] - v;  // exclusive
}

__global__ __launch_bounds__(256) void scan_final_k(const int* __restrict__ in,
                                                    const int* __restrict__ partofs,
                                                    int* __restrict__ out, int L) {
    __shared__ int s[256];
    int t = threadIdx.x, i = blockIdx.x * 256 + t;
    int v = (i < L) ? in[i] : 0;
    s[t] = v;
    __syncthreads();
    for (int off = 1; off < 256; off <<= 1) {
        int x = (t >= off) ? s[t - off] : 0;
        __syncthreads();
        s[t] += x;
        __syncthreads();
    }
    if (i < L) out[i] = partofs[blockIdx.x] + s[t] - v;
}

// ---------------- pass B: multisplit scatter into bucket-grouped ebuf ----------------
// Each (block,bucket) run is contiguous (~16 edges); packed = src(17b) | dst_local(8b)<<17.

__global__ __launch_bounds__(256) void scat_k(const int* __restrict__ src,
                                              const int* __restrict__ dst,
                                              const int* __restrict__ histOfs,
                                              uint_t* __restrict__ ebuf) {
    __shared__ int base[NB];
    __shared__ int lcnt[NB];
    int t = threadIdx.x, blk = blockIdx.x;
    for (int j = t; j < NB; j += 256) {
        base[j] = histOfs[j * GRIDB + blk];
        lcnt[j] = 0;
    }
    __syncthreads();
    int e0 = blk * EPB;
    for (int i = e0 + t; i < e0 + EPB; i += 256) {
        int d = dst[i];
        int b = d >> 8;
        int slot = atomicAdd(&lcnt[b], 1);
        ebuf[base[b] + slot] = (uint_t)src[i] | ((uint_t)(d & 255) << 17);
    }
}

// ---------------- pass C: per-bucket CSR finalize (one block owns a 16KB window) ----------------

__global__ __launch_bounds__(256) void fin_k(const uint_t* __restrict__ ebuf,
                                             const int* __restrict__ histOfs,
                                             int* __restrict__ ofs,
                                             int* __restrict__ esrc) {
    __shared__ int cnt[256];
    __shared__ int s[256];
    __shared__ int fil[256];
    int b = blockIdx.x, t = threadIdx.x;
    int e0 = histOfs[b * GRIDB];
    int e1 = (b == NB - 1) ? N_EDGES : histOfs[(b + 1) * GRIDB];
    cnt[t] = 0;
    __syncthreads();
    for (int i = e0 + t; i < e1; i += 256) atomicAdd(&cnt[ebuf[i] >> 17], 1);
    __syncthreads();
    int c = cnt[t];
    s[t] = c;
    __syncthreads();
    for (int off = 1; off < 256; off <<= 1) {
        int x = (t >= off) ? s[t - off] : 0;
        __syncthreads();
        s[t] += x;
        __syncthreads();
    }
    int excl = s[t] - c;
    int node = b * 256 + t;
    if (node < N_NODES) ofs[node] = e0 + excl;
    if (b == NB - 1 && t == 0) ofs[N_NODES] = N_EDGES;
    fil[t] = excl;
    __syncthreads();
    for (int i = e0 + t; i < e1; i += 256) {
        uint_t u = ebuf[i];
        int slot = atomicAdd(&fil[u >> 17], 1);
        esrc[e0 + slot] = (int)(u & 0x1FFFFu);
    }
}

// ---------------- inverse sqrt degree scales ----------------

__global__ __launch_bounds__(256) void inv_k(const int* __restrict__ dego,
                                             const int* __restrict__ ofs,
                                             float* __restrict__ invo,
                                             float* __restrict__ invi) {
    int i = blockIdx.x * 256 + threadIdx.x;
    if (i < N_NODES) {
        invo[i] = rsqrtf(fmaxf((float)dego[i], 1.0f));
        invi[i] = rsqrtf(fmaxf((float)(ofs[i + 1] - ofs[i]), 1.0f));
    }
}

// ---------------- prep: xs_bf16 = in_feat * invo[row] ----------------

__global__ __launch_bounds__(256) void prep_k(const float* __restrict__ x,
                                              const float* __restrict__ invo,
                                              ushort_t* __restrict__ xs) {
    int gid = blockIdx.x * 256 + threadIdx.x;  // one uint4 (8 elems); grid exact
    int row = gid >> 4;                        // 128/8 == 16 chunks per row
    float s = invo[row];
    const float4* xp = (const float4*)x + (size_t)gid * 2;
    float4 va = xp[0], vb = xp[1];
    ((uint4*)xs)[gid] = make_uint4(pk2(va.x * s, va.y * s), pk2(va.z * s, va.w * s),
                                   pk2(vb.x * s, vb.y * s), pk2(vb.z * s, vb.w * s));
}

// ---------------- agg over 128-dim bf16 rows: one wave/node, quarter-wave per edge ----------------

__global__ __launch_bounds__(256) void agg128_k(const ushort_t* __restrict__ xs,
                                                const int* __restrict__ esrc,
                                                const int* __restrict__ ofs,
                                                const float* __restrict__ invi,
                                                ushort_t* __restrict__ a) {
    int wid = (blockIdx.x * 256 + threadIdx.x) >> 6;
    int lane = threadIdx.x & 63;
    if (wid >= N_NODES) return;
    int q = lane >> 4, li = lane & 15;
    int beg = ofs[wid], end = ofs[wid + 1];
    float acc[8];
    #pragma unroll
    for (int i = 0; i < 8; ++i) acc[i] = 0.f;

    for (int j = beg; j < end; j += 64) {
        int m = end - j;
        if (m > 64) m = 64;
        int idx = (lane < m) ? esrc[j + lane] : 0;
        for (int t = 0; 4 * t < m; ++t) {
            int e = 4 * t + q;
            int s = __shfl(idx, e);
            if (e < m) {
                uint4 v = *(const uint4*)(xs + (size_t)s * 128 + li * 8);
                acc[0] += blo(v.x); acc[1] += bhi(v.x);
                acc[2] += blo(v.y); acc[3] += bhi(v.y);
                acc[4] += blo(v.z); acc[5] += bhi(v.z);
                acc[6] += blo(v.w); acc[7] += bhi(v.w);
            }
        }
    }
    #pragma unroll
    for (int i = 0; i < 8; ++i) acc[i] += __shfl(acc[i], lane ^ 16);
    #pragma unroll
    for (int i = 0; i < 8; ++i) acc[i] += __shfl(acc[i], lane ^ 32);

    if (lane < 16) {
        float sc = invi[wid];
        *(uint4*)(a + (size_t)wid * 128 + li * 8) =
            make_uint4(pk2(acc[0] * sc, acc[1] * sc), pk2(acc[2] * sc, acc[3] * sc),
                       pk2(acc[4] * sc, acc[5] * sc), pk2(acc[6] * sc, acc[7] * sc));
    }
}

// ---------------- agg over 64-dim bf16 rows + bias -> f32 out ----------------

__global__ __launch_bounds__(256) void agg64_k(const ushort_t* __restrict__ ys,
                                               const int* __restrict__ esrc,
                                               const int* __restrict__ ofs,
                                               const float* __restrict__ invi,
                                               const float* __restrict__ b2,
                                               float* __restrict__ out) {
    int wid = (blockIdx.x * 256 + threadIdx.x) >> 6;
    int lane = threadIdx.x & 63;
    if (wid >= N_NODES) return;
    int q = lane >> 4, li = lane & 15;
    int beg = ofs[wid], end = ofs[wid + 1];
    float acc[4];
    #pragma unroll
    for (int i = 0; i < 4; ++i) acc[i] = 0.f;

    for (int j = beg; j < end; j += 64) {
        int m = end - j;
        if (m > 64) m = 64;
        int idx = (lane < m) ? esrc[j + lane] : 0;
        for (int t = 0; 4 * t < m; ++t) {
            int e = 4 * t + q;
            int s = __shfl(idx, e);
            if (e < m) {
                uint2 v = *(const uint2*)(ys + (size_t)s * 64 + li * 4);
                acc[0] += blo(v.x); acc[1] += bhi(v.x);
                acc[2] += blo(v.y); acc[3] += bhi(v.y);
            }
        }
    }
    #pragma unroll
    for (int i = 0; i < 4; ++i) acc[i] += __shfl(acc[i], lane ^ 16);
    #pragma unroll
    for (int i = 0; i < 4; ++i) acc[i] += __shfl(acc[i], lane ^ 32);

    if (lane < 16) {
        float sc = invi[wid];
        float4 b = *(const float4*)(b2 + li * 4);
        *(float4*)(out + (size_t)wid * 64 + li * 4) =
            make_float4(acc[0] * sc + b.x, acc[1] * sc + b.y,
                        acc[2] * sc + b.z, acc[3] * sc + b.w);
    }
}

// ---------------- GEMM: out_bf16[N,BN] = A_bf16[N,128] @ W_f32[128,BN] (+bias)(relu)(*oscale) ----------------

template <int BN, int TR, bool ADD_BIAS, bool RELU, bool SCALE_OUT>
__global__ __launch_bounds__(256) void gemm_k(const ushort_t* __restrict__ A,
                                              const float* __restrict__ W,
                                              const float* __restrict__ bias,
                                              const float* __restrict__ oscale,
                                              ushort_t* __restrict__ out) {
    constexpr int K = 128;
    constexpr int BM = 32;
    constexpr int CG = BN / 8;
    constexpr int RG = 256 / CG;
    static_assert(RG * TR == BM, "tile mismatch");

    __shared__ ushort_t Wsb[K * BN];  // bf16
    __shared__ float As[BM * (K + 1)];

    int t = threadIdx.x;
    int row0 = blockIdx.x * BM;

    for (int i = t; i < K * BN / 4; i += 256) {
        float4 v = ((const float4*)W)[i];
        ((uint2*)Wsb)[i] = make_uint2(pk2(v.x, v.y), pk2(v.z, v.w));
    }
    for (int i = t; i < BM * K / 8; i += 256) {
        int r = i >> 4;
        int c = i & 15;
        uint4 v = ((const uint4*)(A + (size_t)(row0 + r) * K))[c];
        float* dp = &As[r * (K + 1) + c * 8];
        dp[0] = blo(v.x); dp[1] = bhi(v.x);
        dp[2] = blo(v.y); dp[3] = bhi(v.y);
        dp[4] = blo(v.z); dp[5] = bhi(v.z);
        dp[6] = blo(v.w); dp[7] = bhi(v.w);
    }
    __syncthreads();

    int cg = t % CG, rg = t / CG;
    int j0 = cg * 4, j1 = BN / 2 + cg * 4;

    float acc[TR][8];
    #pragma unroll
    for (int i = 0; i < TR; ++i)
        #pragma unroll
        for (int j = 0; j < 8; ++j) acc[i][j] = 0.0f;

    #pragma unroll 4
    for (int k = 0; k < K; ++k) {
        uint2 wa = *(const uint2*)&Wsb[k * BN + j0];
        uint2 wb = *(const uint2*)&Wsb[k * BN + j1];
        float wv[8];
        wv[0] = blo(wa.x); wv[1] = bhi(wa.x); wv[2] = blo(wa.y); wv[3] = bhi(wa.y);
        wv[4] = blo(wb.x); wv[5] = bhi(wb.x); wv[6] = blo(wb.y); wv[7] = bhi(wb.y);
        #pragma unroll
        for (int i = 0; i < TR; ++i) {
            float a = As[(rg * TR + i) * (K + 1) + k];
            #pragma unroll
            for (int j = 0; j < 8; ++j) acc[i][j] += a * wv[j];
        }
    }

    #pragma unroll
    for (int i = 0; i < TR; ++i) {
        int row = row0 + rg * TR + i;
        float os = SCALE_OUT ? oscale[row] : 1.0f;
        float v[8];
        #pragma unroll
        for (int j = 0; j < 8; ++j) {
            float x = acc[i][j];
            if (ADD_BIAS) x += bias[(j < 4) ? (j0 + j) : (j1 + j - 4)];
            if (RELU) x = fmaxf(x, 0.0f);
            if (SCALE_OUT) x *= os;
            v[j] = x;
        }
        ushort_t* op = out + (size_t)row * BN;
        *(uint2*)(op + j0) = make_uint2(pk2(v[0], v[1]), pk2(v[2], v[3]));
        *(uint2*)(op + j1) = make_uint2(pk2(v[4], v[5]), pk2(v[6], v[7]));
    }
}

extern "C" void kernel_launch(void* const* d_in, const int* in_sizes, int n_in,
                              void* d_out, int out_size, void* d_ws, size_t ws_size,
                              hipStream_t stream) {
    const float* in_feat = (const float*)d_in[0];
    const float* W1 = (const float*)d_in[1];
    const float* b1 = (const float*)d_in[2];
    const float* W2 = (const float*)d_in[3];
    const float* b2 = (const float*)d_in[4];
    const int* src = (const int*)d_in[5];
    const int* dst = (const int*)d_in[6];
    float* out = (float*)d_out;

    // workspace layout (16B-aligned slots)
    char* w = (char*)d_ws;
    int* dego = (int*)w;       w += (size_t)N_NODES * 4;
    float* invo = (float*)w;   w += (size_t)N_NODES * 4;
    float* invi = (float*)w;   w += (size_t)N_NODES * 4;
    int* ofs = (int*)w;        w += (size_t)(N_NODES + 4) * 4;
    int* hist = (int*)w;       w += (size_t)CELLS * 4;
    int* histOfs = (int*)w;    w += (size_t)CELLS * 4;
    int* partial = (int*)w;    w += 512 * 4;
    int* partofs = (int*)w;    w += 512 * 4;
    uint_t* ebuf = (uint_t*)w; w += (size_t)N_EDGES * 4;
    int* esrc = (int*)w;       w += (size_t)N_EDGES * 4;
    ushort_t* bufA = (ushort_t*)w; w += (size_t)N_NODES * HID_DIM * 2;  // xs -> h
    ushort_t* bufB = (ushort_t*)w; w += (size_t)N_NODES * HID_DIM * 2;  // a -> ys

    // out-degrees (src side)
    hipMemsetAsync(dego, 0, (size_t)N_NODES * 4, stream);
    deg_k<<<(N_EDGES + 255) / 256, 256, 0, stream>>>(src, dego);

    // CSR by dst via bucketed counting sort (LDS atomics only)
    hist_k<<<GRIDB, 256, 0, stream>>>(dst, hist);
    scan_part_k<<<SNPART, 256, 0, stream>>>(hist, partial, CELLS);
    scan_top_k<<<1, 512, 0, stream>>>(partial, partofs, SNPART);
    scan_final_k<<<SNPART, 256, 0, stream>>>(hist, partofs, histOfs, CELLS);
    scat_k<<<GRIDB, 256, 0, stream>>>(src, dst, histOfs, ebuf);
    fin_k<<<NB, 256, 0, stream>>>(ebuf, histOfs, ofs, esrc);

    inv_k<<<(N_NODES + 255) / 256, 256, 0, stream>>>(dego, ofs, invo, invi);

    // layer 1: xs = bf16(x*invo); a = bf16(invi*Agg(xs)); h = bf16(relu(a@W1+b1))
    prep_k<<<N_NODES * 16 / 256, 256, 0, stream>>>(in_feat, invo, bufA);
    agg128_k<<<N_NODES / 4, 256, 0, stream>>>(bufA, esrc, ofs, invi, bufB);
    gemm_k<HID_DIM, 2, true, true, false><<<N_NODES / 32, 256, 0, stream>>>(bufB, W1, b1, nullptr, bufA);

    // layer 2: ys = bf16((h@W2)*invo); out = invi*Agg(ys) + b2
    gemm_k<OUT_DIM, 1, false, false, true><<<N_NODES / 32, 256, 0, stream>>>(bufA, W2, nullptr, invo, bufB);
    agg64_k<<<N_NODES / 4, 256, 0, stream>>>(bufB, esrc, ofs, invi, b2, out);
}

// Round 8
// 298.564 us; speedup vs baseline: 14.5639x; 1.2807x over previous
//
#include <hip/hip_runtime.h>

#define N_NODES 100000
#define N_EDGES 1600000
#define IN_DIM 128
#define HID_DIM 128
#define OUT_DIM 64

// ---- bucketed CSR sort geometry ----
#define NB 391                      // buckets: dst>>8, ceil(100000/256)
#define GRIDB 256                   // blocks in hist/scat passes
#define EPB (N_EDGES / GRIDB)       // 6250 edges per block (exact)
#define CELLS (NB * GRIDB)          // 100096 (exact multiple of 256)
#define SNPART (CELLS / 256)        // 391 scan partials

typedef unsigned short ushort_t;
typedef unsigned int uint_t;
typedef __attribute__((ext_vector_type(8))) short bf16x8;
typedef __attribute__((ext_vector_type(4))) float f32x4;

// bf16 helpers (manual, RNE pack / shift unpack)
__device__ __forceinline__ float blo(uint_t u) { return __uint_as_float(u << 16); }
__device__ __forceinline__ float bhi(uint_t u) { return __uint_as_float(u & 0xFFFF0000u); }
__device__ __forceinline__ uint_t f2b(float f) {
    uint_t u = __float_as_uint(f);
    uint_t r = u + 0x7FFFu + ((u >> 16) & 1u);
    return r >> 16;
}
__device__ __forceinline__ uint_t pk2(float a, float b) { return f2b(a) | (f2b(b) << 16); }

// ---------------- out-degrees (src side) ----------------

__global__ __launch_bounds__(256) void deg_k(const int* __restrict__ src,
                                             int* __restrict__ dego) {
    int i = blockIdx.x * 256 + threadIdx.x;
    if (i < N_EDGES) atomicAdd(&dego[src[i]], 1);
}

// ---------------- pass A: per-block bucket histogram (LDS atomics only) ----------------

__global__ __launch_bounds__(256) void hist_k(const int* __restrict__ dst,
                                              int* __restrict__ hist) {
    __shared__ int h[NB];
    int t = threadIdx.x, blk = blockIdx.x;
    for (int j = t; j < NB; j += 256) h[j] = 0;
    __syncthreads();
    int e0 = blk * EPB;
    for (int i = e0 + t; i < e0 + EPB; i += 256) atomicAdd(&h[dst[i] >> 8], 1);
    __syncthreads();
    for (int j = t; j < NB; j += 256) hist[j * GRIDB + blk] = h[j];  // bucket-major
}

// ---------------- flat exclusive scan ----------------

__global__ __launch_bounds__(256) void scan_part_k(const int* __restrict__ in,
                                                   int* __restrict__ partial, int L) {
    __shared__ int s[256];
    int t = threadIdx.x, i = blockIdx.x * 256 + t;
    s[t] = (i < L) ? in[i] : 0;
    __syncthreads();
    for (int off = 128; off > 0; off >>= 1) {
        if (t < off) s[t] += s[t + off];
        __syncthreads();
    }
    if (t == 0) partial[blockIdx.x] = s[0];
}

__global__ __launch_bounds__(512) void scan_top_k(const int* __restrict__ partial,
                                                  int* __restrict__ partofs, int n) {
    __shared__ int s[512];
    int t = threadIdx.x;
    int v = (t < n) ? partial[t] : 0;
    s[t] = v;
    __syncthreads();
    for (int off = 1; off < 512; off <<= 1) {
        int x = (t >= off) ? s[t - off] : 0;
        __syncthreads();
        s[t] += x;
        __syncthreads();
    }
    if (t < n) partofs[t] = s[t] - v;  // exclusive
}

__global__ __launch_bounds__(256) void scan_final_k(const int* __restrict__ in,
                                                    const int* __restrict__ partofs,
                                                    int* __restrict__ out, int L) {
    __shared__ int s[256];
    int t = threadIdx.x, i = blockIdx.x * 256 + t;
    int v = (i < L) ? in[i] : 0;
    s[t] = v;
    __syncthreads();
    for (int off = 1; off < 256; off <<= 1) {
        int x = (t >= off) ? s[t - off] : 0;
        __syncthreads();
        s[t] += x;
        __syncthreads();
    }
    if (i < L) out[i] = partofs[blockIdx.x] + s[t] - v;
}

// ---------------- pass B: multisplit scatter ----------------

__global__ __launch_bounds__(256) void scat_k(const int* __restrict__ src,
                                              const int* __restrict__ dst,
                                              const int* __restrict__ histOfs,
                                              uint_t* __restrict__ ebuf) {
    __shared__ int base[NB];
    __shared__ int lcnt[NB];
    int t = threadIdx.x, blk = blockIdx.x;
    for (int j = t; j < NB; j += 256) {
        base[j] = histOfs[j * GRIDB + blk];
        lcnt[j] = 0;
    }
    __syncthreads();
    int e0 = blk * EPB;
    for (int i = e0 + t; i < e0 + EPB; i += 256) {
        int d = dst[i];
        int b = d >> 8;
        int slot = atomicAdd(&lcnt[b], 1);
        ebuf[base[b] + slot] = (uint_t)src[i] | ((uint_t)(d & 255) << 17);
    }
}

// ---------------- pass C: per-bucket CSR finalize ----------------

__global__ __launch_bounds__(256) void fin_k(const uint_t* __restrict__ ebuf,
                                             const int* __restrict__ histOfs,
                                             int* __restrict__ ofs,
                                             int* __restrict__ esrc) {
    __shared__ int cnt[256];
    __shared__ int s[256];
    __shared__ int fil[256];
    int b = blockIdx.x, t = threadIdx.x;
    int e0 = histOfs[b * GRIDB];
    int e1 = (b == NB - 1) ? N_EDGES : histOfs[(b + 1) * GRIDB];
    cnt[t] = 0;
    __syncthreads();
    for (int i = e0 + t; i < e1; i += 256) atomicAdd(&cnt[ebuf[i] >> 17], 1);
    __syncthreads();
    int c = cnt[t];
    s[t] = c;
    __syncthreads();
    for (int off = 1; off < 256; off <<= 1) {
        int x = (t >= off) ? s[t - off] : 0;
        __syncthreads();
        s[t] += x;
        __syncthreads();
    }
    int excl = s[t] - c;
    int node = b * 256 + t;
    if (node < N_NODES) ofs[node] = e0 + excl;
    if (b == NB - 1 && t == 0) ofs[N_NODES] = N_EDGES;
    fil[t] = excl;
    __syncthreads();
    for (int i = e0 + t; i < e1; i += 256) {
        uint_t u = ebuf[i];
        int slot = atomicAdd(&fil[u >> 17], 1);
        esrc[e0 + slot] = (int)(u & 0x1FFFFu);
    }
}

// ---------------- inverse sqrt degree scales ----------------

__global__ __launch_bounds__(256) void inv_k(const int* __restrict__ dego,
                                             const int* __restrict__ ofs,
                                             float* __restrict__ invo,
                                             float* __restrict__ invi) {
    int i = blockIdx.x * 256 + threadIdx.x;
    if (i < N_NODES) {
        invo[i] = rsqrtf(fmaxf((float)dego[i], 1.0f));
        invi[i] = rsqrtf(fmaxf((float)(ofs[i + 1] - ofs[i]), 1.0f));
    }
}

// ---------------- prep: xs_bf16 = in_feat * invo[row] ----------------

__global__ __launch_bounds__(256) void prep_k(const float* __restrict__ x,
                                              const float* __restrict__ invo,
                                              ushort_t* __restrict__ xs) {
    int gid = blockIdx.x * 256 + threadIdx.x;  // one uint4 (8 elems); grid exact
    int row = gid >> 4;                        // 128/8 == 16 chunks per row
    float s = invo[row];
    const float4* xp = (const float4*)x + (size_t)gid * 2;
    float4 va = xp[0], vb = xp[1];
    ((uint4*)xs)[gid] = make_uint4(pk2(va.x * s, va.y * s), pk2(va.z * s, va.w * s),
                                   pk2(vb.x * s, vb.y * s), pk2(vb.z * s, vb.w * s));
}

// ---------------- W fragment pack: Wf[(nt*4+kc)*64 + lane] = 8 bf16 (16B) ----------------
// lane l supplies B[k = kc*32 + (l>>4)*8 + e][col = nt*16 + (l&15)] for e=0..7.
// k-slot permutation cancels between A and B frags; only C/D layout must be exact.

__global__ __launch_bounds__(256) void wprep_k(const float* __restrict__ W,
                                               ushort_t* __restrict__ Wf, int BN) {
    int gid = blockIdx.x * 256 + threadIdx.x;  // total = BN*16
    if (gid >= BN * 16) return;
    int l = gid & 63;
    int kc = (gid >> 6) & 3;
    int nt = gid >> 8;
    int col = nt * 16 + (l & 15);
    int k0 = kc * 32 + (l >> 4) * 8;
    uint_t r[4];
    #pragma unroll
    for (int p = 0; p < 4; ++p)
        r[p] = pk2(W[(size_t)(k0 + 2 * p) * BN + col], W[(size_t)(k0 + 2 * p + 1) * BN + col]);
    ((uint4*)Wf)[gid] = make_uint4(r[0], r[1], r[2], r[3]);
}

// ---------------- MFMA GEMM: out_bf16[N,BN] = A_bf16[N,128] @ Wf (+bias)(relu)(*oscale) ----------------
// One wave = 16 rows x BN cols. 100000 % 16 == 0, so active waves are always full.

template <int BN, bool ADD_BIAS, bool RELU, bool SCALE_OUT>
__global__ __launch_bounds__(256) void mgemm_k(const ushort_t* __restrict__ A,
                                               const ushort_t* __restrict__ Wf,
                                               const float* __restrict__ bias,
                                               const float* __restrict__ oscale,
                                               ushort_t* __restrict__ out) {
    constexpr int NT = BN / 16;
    int wv = threadIdx.x >> 6;
    int l = threadIdx.x & 63;
    int r0 = (blockIdx.x * 4 + wv) * 16;
    if (r0 >= N_NODES) return;

    // A fragments: lane l -> row r0+(l&15), k-slots (l>>4)*8.. per kc
    const ushort_t* ap = A + (size_t)(r0 + (l & 15)) * 128 + (l >> 4) * 8;
    bf16x8 af[4];
    #pragma unroll
    for (int kc = 0; kc < 4; ++kc) af[kc] = *(const bf16x8*)(ap + kc * 32);

    f32x4 acc[NT];
    #pragma unroll
    for (int nt = 0; nt < NT; ++nt) acc[nt] = (f32x4){0.f, 0.f, 0.f, 0.f};

    #pragma unroll
    for (int kc = 0; kc < 4; ++kc) {
        #pragma unroll
        for (int nt = 0; nt < NT; ++nt) {
            bf16x8 bf = *(const bf16x8*)(Wf + ((size_t)(nt * 4 + kc) * 64 + l) * 8);
            acc[nt] = __builtin_amdgcn_mfma_f32_16x16x32_bf16(af[kc], bf, acc[nt], 0, 0, 0);
        }
    }

    // C/D: lane l, reg j -> row r0+(l>>4)*4+j, col nt*16+(l&15)   [m89-verified]
    int orow = r0 + (l >> 4) * 4;
    int col = l & 15;
    float os[4];
    if (SCALE_OUT) {
        #pragma unroll
        for (int j = 0; j < 4; ++j) os[j] = oscale[orow + j];
    }
    #pragma unroll
    for (int nt = 0; nt < NT; ++nt) {
        float bv = ADD_BIAS ? bias[nt * 16 + col] : 0.f;
        #pragma unroll
        for (int j = 0; j < 4; ++j) {
            float x = acc[nt][j];
            if (ADD_BIAS) x += bv;
            if (RELU) x = fmaxf(x, 0.0f);
            if (SCALE_OUT) x *= os[j];
            out[(size_t)(orow + j) * BN + nt * 16 + col] = (ushort_t)f2b(x);
        }
    }
}

// ---------------- agg over 128-dim bf16 rows: one wave/node, quarter-wave per edge, 4x unrolled ----------------

#define ACC8(v)                                         \
    acc[0] += blo(v.x); acc[1] += bhi(v.x);             \
    acc[2] += blo(v.y); acc[3] += bhi(v.y);             \
    acc[4] += blo(v.z); acc[5] += bhi(v.z);             \
    acc[6] += blo(v.w); acc[7] += bhi(v.w);

__global__ __launch_bounds__(256) void agg128_k(const ushort_t* __restrict__ xs,
                                                const int* __restrict__ esrc,
                                                const int* __restrict__ ofs,
                                                const float* __restrict__ invi,
                                                ushort_t* __restrict__ a) {
    int wid = (blockIdx.x * 256 + threadIdx.x) >> 6;
    int lane = threadIdx.x & 63;
    if (wid >= N_NODES) return;
    int q = lane >> 4, li = lane & 15;
    int beg = ofs[wid], end = ofs[wid + 1];
    float acc[8];
    #pragma unroll
    for (int i = 0; i < 8; ++i) acc[i] = 0.f;

    for (int j = beg; j < end; j += 64) {
        int m = end - j;
        if (m > 64) m = 64;
        int idx = (lane < m) ? esrc[j + lane] : 0;
        for (int t = 0; 4 * t < m; t += 4) {
            int e0 = 4 * t + q, e1 = e0 + 4, e2 = e0 + 8, e3 = e0 + 12;
            int s0 = __shfl(idx, e0 & 63);
            int s1 = __shfl(idx, e1 & 63);
            int s2 = __shfl(idx, e2 & 63);
            int s3 = __shfl(idx, e3 & 63);
            uint4 v0 = *(const uint4*)(xs + (size_t)s0 * 128 + li * 8);
            uint4 v1 = *(const uint4*)(xs + (size_t)s1 * 128 + li * 8);
            uint4 v2 = *(const uint4*)(xs + (size_t)s2 * 128 + li * 8);
            uint4 v3 = *(const uint4*)(xs + (size_t)s3 * 128 + li * 8);
            if (e0 < m) { ACC8(v0) }
            if (e1 < m) { ACC8(v1) }
            if (e2 < m) { ACC8(v2) }
            if (e3 < m) { ACC8(v3) }
        }
    }
    #pragma unroll
    for (int i = 0; i < 8; ++i) acc[i] += __shfl(acc[i], lane ^ 16);
    #pragma unroll
    for (int i = 0; i < 8; ++i) acc[i] += __shfl(acc[i], lane ^ 32);

    if (lane < 16) {
        float sc = invi[wid];
        *(uint4*)(a + (size_t)wid * 128 + li * 8) =
            make_uint4(pk2(acc[0] * sc, acc[1] * sc), pk2(acc[2] * sc, acc[3] * sc),
                       pk2(acc[4] * sc, acc[5] * sc), pk2(acc[6] * sc, acc[7] * sc));
    }
}

#define ACC4(v)                                         \
    acc[0] += blo(v.x); acc[1] += bhi(v.x);             \
    acc[2] += blo(v.y); acc[3] += bhi(v.y);

__global__ __launch_bounds__(256) void agg64_k(const ushort_t* __restrict__ ys,
                                               const int* __restrict__ esrc,
                                               const int* __restrict__ ofs,
                                               const float* __restrict__ invi,
                                               const float* __restrict__ b2,
                                               float* __restrict__ out) {
    int wid = (blockIdx.x * 256 + threadIdx.x) >> 6;
    int lane = threadIdx.x & 63;
    if (wid >= N_NODES) return;
    int q = lane >> 4, li = lane & 15;
    int beg = ofs[wid], end = ofs[wid + 1];
    float acc[4];
    #pragma unroll
    for (int i = 0; i < 4; ++i) acc[i] = 0.f;

    for (int j = beg; j < end; j += 64) {
        int m = end - j;
        if (m > 64) m = 64;
        int idx = (lane < m) ? esrc[j + lane] : 0;
        for (int t = 0; 4 * t < m; t += 4) {
            int e0 = 4 * t + q, e1 = e0 + 4, e2 = e0 + 8, e3 = e0 + 12;
            int s0 = __shfl(idx, e0 & 63);
            int s1 = __shfl(idx, e1 & 63);
            int s2 = __shfl(idx, e2 & 63);
            int s3 = __shfl(idx, e3 & 63);
            uint2 v0 = *(const uint2*)(ys + (size_t)s0 * 64 + li * 4);
            uint2 v1 = *(const uint2*)(ys + (size_t)s1 * 64 + li * 4);
            uint2 v2 = *(const uint2*)(ys + (size_t)s2 * 64 + li * 4);
            uint2 v3 = *(const uint2*)(ys + (size_t)s3 * 64 + li * 4);
            if (e0 < m) { ACC4(v0) }
            if (e1 < m) { ACC4(v1) }
            if (e2 < m) { ACC4(v2) }
            if (e3 < m) { ACC4(v3) }
        }
    }
    #pragma unroll
    for (int i = 0; i < 4; ++i) acc[i] += __shfl(acc[i], lane ^ 16);
    #pragma unroll
    for (int i = 0; i < 4; ++i) acc[i] += __shfl(acc[i], lane ^ 32);

    if (lane < 16) {
        float sc = invi[wid];
        float4 b = *(const float4*)(b2 + li * 4);
        *(float4*)(out + (size_t)wid * 64 + li * 4) =
            make_float4(acc[0] * sc + b.x, acc[1] * sc + b.y,
                        acc[2] * sc + b.z, acc[3] * sc + b.w);
    }
}

extern "C" void kernel_launch(void* const* d_in, const int* in_sizes, int n_in,
                              void* d_out, int out_size, void* d_ws, size_t ws_size,
                              hipStream_t stream) {
    const float* in_feat = (const float*)d_in[0];
    const float* W1 = (const float*)d_in[1];
    const float* b1 = (const float*)d_in[2];
    const float* W2 = (const float*)d_in[3];
    const float* b2 = (const float*)d_in[4];
    const int* src = (const int*)d_in[5];
    const int* dst = (const int*)d_in[6];
    float* out = (float*)d_out;

    // workspace layout (16B-aligned slots)
    char* w = (char*)d_ws;
    int* dego = (int*)w;       w += (size_t)N_NODES * 4;
    float* invo = (float*)w;   w += (size_t)N_NODES * 4;
    float* invi = (float*)w;   w += (size_t)N_NODES * 4;
    int* ofs = (int*)w;        w += (size_t)(N_NODES + 4) * 4;
    int* hist = (int*)w;       w += (size_t)CELLS * 4;
    int* histOfs = (int*)w;    w += (size_t)CELLS * 4;
    int* partial = (int*)w;    w += 512 * 4;
    int* partofs = (int*)w;    w += 512 * 4;
    uint_t* ebuf = (uint_t*)w; w += (size_t)N_EDGES * 4;
    int* esrc = (int*)w;       w += (size_t)N_EDGES * 4;
    ushort_t* Wf1 = (ushort_t*)w; w += (size_t)HID_DIM * 16 * 16;  // 32 KB frag-packed W1
    ushort_t* Wf2 = (ushort_t*)w; w += (size_t)OUT_DIM * 16 * 16;  // 16 KB frag-packed W2
    ushort_t* bufA = (ushort_t*)w; w += (size_t)N_NODES * HID_DIM * 2;  // xs -> h
    ushort_t* bufB = (ushort_t*)w; w += (size_t)N_NODES * HID_DIM * 2;  // a -> ys

    // out-degrees (src side)
    hipMemsetAsync(dego, 0, (size_t)N_NODES * 4, stream);
    deg_k<<<(N_EDGES + 255) / 256, 256, 0, stream>>>(src, dego);

    // CSR by dst via bucketed counting sort (LDS atomics only)
    hist_k<<<GRIDB, 256, 0, stream>>>(dst, hist);
    scan_part_k<<<SNPART, 256, 0, stream>>>(hist, partial, CELLS);
    scan_top_k<<<1, 512, 0, stream>>>(partial, partofs, SNPART);
    scan_final_k<<<SNPART, 256, 0, stream>>>(hist, partofs, histOfs, CELLS);
    scat_k<<<GRIDB, 256, 0, stream>>>(src, dst, histOfs, ebuf);
    fin_k<<<NB, 256, 0, stream>>>(ebuf, histOfs, ofs, esrc);

    inv_k<<<(N_NODES + 255) / 256, 256, 0, stream>>>(dego, ofs, invo, invi);

    // pack W fragments (tiny, independent)
    wprep_k<<<(HID_DIM * 16 + 255) / 256, 256, 0, stream>>>(W1, Wf1, HID_DIM);
    wprep_k<<<(OUT_DIM * 16 + 255) / 256, 256, 0, stream>>>(W2, Wf2, OUT_DIM);

    // layer 1: xs = bf16(x*invo); a = bf16(invi*Agg(xs)); h = bf16(relu(a@W1+b1))
    prep_k<<<N_NODES * 16 / 256, 256, 0, stream>>>(in_feat, invo, bufA);
    agg128_k<<<N_NODES / 4, 256, 0, stream>>>(bufA, esrc, ofs, invi, bufB);
    mgemm_k<HID_DIM, true, true, false><<<(N_NODES / 16 + 3) / 4, 256, 0, stream>>>(bufB, Wf1, b1, nullptr, bufA);

    // layer 2: ys = bf16((h@W2)*invo); out = invi*Agg(ys) + b2
    mgemm_k<OUT_DIM, false, false, true><<<(N_NODES / 16 + 3) / 4, 256, 0, stream>>>(bufA, Wf2, nullptr, invo, bufB);
    agg64_k<<<N_NODES / 4, 256, 0, stream>>>(bufB, esrc, ofs, invi, b2, out);
}

// Round 9
// 290.613 us; speedup vs baseline: 14.9624x; 1.0274x over previous
//
#include <hip/hip_runtime.h>

#define N_NODES 100000
#define N_EDGES 1600000
#define IN_DIM 128
#define HID_DIM 128
#define OUT_DIM 64

// ---- bucketed CSR sort geometry ----
#define NB 391                      // buckets: dst>>8, ceil(100000/256)
#define GRIDB 256                   // blocks in hist/scat passes
#define EPB (N_EDGES / GRIDB)       // 6250 edges per block (exact)
#define CELLS (NB * GRIDB)          // 100096 (exact multiple of 256)
#define SNPART (CELLS / 256)        // 391 scan partials

typedef unsigned short ushort_t;
typedef unsigned int uint_t;
typedef __attribute__((ext_vector_type(8))) short bf16x8;
typedef __attribute__((ext_vector_type(4))) float f32x4;

// bf16 helpers (manual, RNE pack / shift unpack)
__device__ __forceinline__ float blo(uint_t u) { return __uint_as_float(u << 16); }
__device__ __forceinline__ float bhi(uint_t u) { return __uint_as_float(u & 0xFFFF0000u); }
__device__ __forceinline__ uint_t f2b(float f) {
    uint_t u = __float_as_uint(f);
    uint_t r = u + 0x7FFFu + ((u >> 16) & 1u);
    return r >> 16;
}
__device__ __forceinline__ uint_t pk2(float a, float b) { return f2b(a) | (f2b(b) << 16); }

// ---------------- pass A: bucket histogram (LDS atomics) + src out-degrees ----------------

__global__ __launch_bounds__(256) void histdeg_k(const int* __restrict__ src,
                                                 const int* __restrict__ dst,
                                                 int* __restrict__ dego,
                                                 int* __restrict__ hist) {
    __shared__ int h[NB];
    int t = threadIdx.x, blk = blockIdx.x;
    for (int j = t; j < NB; j += 256) h[j] = 0;
    __syncthreads();
    int e0 = blk * EPB;
    for (int i = e0 + t; i < e0 + EPB; i += 256) {
        atomicAdd(&h[dst[i] >> 8], 1);
        atomicAdd(&dego[src[i]], 1);
    }
    __syncthreads();
    for (int j = t; j < NB; j += 256) hist[j * GRIDB + blk] = h[j];  // bucket-major
}

// ---------------- flat exclusive scan ----------------

__global__ __launch_bounds__(256) void scan_part_k(const int* __restrict__ in,
                                                   int* __restrict__ partial, int L) {
    __shared__ int s[256];
    int t = threadIdx.x, i = blockIdx.x * 256 + t;
    s[t] = (i < L) ? in[i] : 0;
    __syncthreads();
    for (int off = 128; off > 0; off >>= 1) {
        if (t < off) s[t] += s[t + off];
        __syncthreads();
    }
    if (t == 0) partial[blockIdx.x] = s[0];
}

__global__ __launch_bounds__(512) void scan_top_k(const int* __restrict__ partial,
                                                  int* __restrict__ partofs, int n) {
    __shared__ int s[512];
    int t = threadIdx.x;
    int v = (t < n) ? partial[t] : 0;
    s[t] = v;
    __syncthreads();
    for (int off = 1; off < 512; off <<= 1) {
        int x = (t >= off) ? s[t - off] : 0;
        __syncthreads();
        s[t] += x;
        __syncthreads();
    }
    if (t < n) partofs[t] = s[t] - v;  // exclusive
}

__global__ __launch_bounds__(256) void scan_final_k(const int* __restrict__ in,
                                                    const int* __restrict__ partofs,
                                                    int* __restrict__ out, int L) {
    __shared__ int s[256];
    int t = threadIdx.x, i = blockIdx.x * 256 + t;
    int v = (i < L) ? in[i] : 0;
    s[t] = v;
    __syncthreads();
    for (int off = 1; off < 256; off <<= 1) {
        int x = (t >= off) ? s[t - off] : 0;
        __syncthreads();
        s[t] += x;
        __syncthreads();
    }
    if (i < L) out[i] = partofs[blockIdx.x] + s[t] - v;
}

// ---------------- pass B: multisplit scatter ----------------

__global__ __launch_bounds__(256) void scat_k(const int* __restrict__ src,
                                              const int* __restrict__ dst,
                                              const int* __restrict__ histOfs,
                                              uint_t* __restrict__ ebuf) {
    __shared__ int base[NB];
    __shared__ int lcnt[NB];
    int t = threadIdx.x, blk = blockIdx.x;
    for (int j = t; j < NB; j += 256) {
        base[j] = histOfs[j * GRIDB + blk];
        lcnt[j] = 0;
    }
    __syncthreads();
    int e0 = blk * EPB;
    for (int i = e0 + t; i < e0 + EPB; i += 256) {
        int d = dst[i];
        int b = d >> 8;
        int slot = atomicAdd(&lcnt[b], 1);
        ebuf[base[b] + slot] = (uint_t)src[i] | ((uint_t)(d & 255) << 17);
    }
}

// ---------------- pass C: per-bucket CSR finalize ----------------

__global__ __launch_bounds__(256) void fin_k(const uint_t* __restrict__ ebuf,
                                             const int* __restrict__ histOfs,
                                             int* __restrict__ ofs,
                                             int* __restrict__ esrc) {
    __shared__ int cnt[256];
    __shared__ int s[256];
    __shared__ int fil[256];
    int b = blockIdx.x, t = threadIdx.x;
    int e0 = histOfs[b * GRIDB];
    int e1 = (b == NB - 1) ? N_EDGES : histOfs[(b + 1) * GRIDB];
    cnt[t] = 0;
    __syncthreads();
    for (int i = e0 + t; i < e1; i += 256) atomicAdd(&cnt[ebuf[i] >> 17], 1);
    __syncthreads();
    int c = cnt[t];
    s[t] = c;
    __syncthreads();
    for (int off = 1; off < 256; off <<= 1) {
        int x = (t >= off) ? s[t - off] : 0;
        __syncthreads();
        s[t] += x;
        __syncthreads();
    }
    int excl = s[t] - c;
    int node = b * 256 + t;
    if (node < N_NODES) ofs[node] = e0 + excl;
    if (b == NB - 1 && t == 0) ofs[N_NODES] = N_EDGES;
    fil[t] = excl;
    __syncthreads();
    for (int i = e0 + t; i < e1; i += 256) {
        uint_t u = ebuf[i];
        int slot = atomicAdd(&fil[u >> 17], 1);
        esrc[e0 + slot] = (int)(u & 0x1FFFFu);
    }
}

// ---------------- prep: xs_bf16 = in_feat * rsqrt(dego) ----------------

__global__ __launch_bounds__(256) void prep_k(const float* __restrict__ x,
                                              const int* __restrict__ dego,
                                              ushort_t* __restrict__ xs) {
    int gid = blockIdx.x * 256 + threadIdx.x;  // one uint4 (8 elems); grid exact
    int row = gid >> 4;                        // 128/8 == 16 chunks per row
    float s = rsqrtf(fmaxf((float)dego[row], 1.0f));
    const float4* xp = (const float4*)x + (size_t)gid * 2;
    float4 va = xp[0], vb = xp[1];
    ((uint4*)xs)[gid] = make_uint4(pk2(va.x * s, va.y * s), pk2(va.z * s, va.w * s),
                                   pk2(vb.x * s, vb.y * s), pk2(vb.z * s, vb.w * s));
}

// ---------------- W fragment pack: Wf[(nt*4+kc)*64 + lane] = 8 bf16 (16B) ----------------
// lane l supplies B[k = kc*32 + (l>>4)*8 + e][col = nt*16 + (l&15)] for e=0..7.

__global__ __launch_bounds__(256) void wprep_k(const float* __restrict__ W,
                                               ushort_t* __restrict__ Wf, int BN) {
    int gid = blockIdx.x * 256 + threadIdx.x;  // total = BN*16
    if (gid >= BN * 16) return;
    int l = gid & 63;
    int kc = (gid >> 6) & 3;
    int nt = gid >> 8;
    int col = nt * 16 + (l & 15);
    int k0 = kc * 32 + (l >> 4) * 8;
    uint_t r[4];
    #pragma unroll
    for (int p = 0; p < 4; ++p)
        r[p] = pk2(W[(size_t)(k0 + 2 * p) * BN + col], W[(size_t)(k0 + 2 * p + 1) * BN + col]);
    ((uint4*)Wf)[gid] = make_uint4(r[0], r[1], r[2], r[3]);
}

#define ACC8(v)                                         \
    acc[0] += blo(v.x); acc[1] += bhi(v.x);             \
    acc[2] += blo(v.y); acc[3] += bhi(v.y);             \
    acc[4] += blo(v.z); acc[5] += bhi(v.z);             \
    acc[6] += blo(v.w); acc[7] += bhi(v.w);

// ---------------- FUSED agg128 + mgemm1 ----------------
// 4 waves/block; each wave owns 16 consecutive nodes: gather-reduce each node's
// 128-d row (quarter-wave, 4 edges in flight), stage to a per-wave LDS tile
// (272 B padded rows -> conflict-free ds_read_b128), then MFMA h = relu(a@W1+b1).

__global__ __launch_bounds__(256) void aggmm128_k(const ushort_t* __restrict__ xs,
                                                  const int* __restrict__ esrc,
                                                  const int* __restrict__ ofs,
                                                  const ushort_t* __restrict__ Wf,
                                                  const float* __restrict__ bias,
                                                  ushort_t* __restrict__ h) {
    __shared__ ushort_t As[4][16][136];  // 136 ushorts = 272 B row stride
    int wv = threadIdx.x >> 6;
    int l = threadIdx.x & 63;
    int base = blockIdx.x * 64 + wv * 16;
    if (base >= N_NODES) return;
    int q = l >> 4, li = l & 15;

    for (int nn = 0; nn < 16; ++nn) {
        int node = base + nn;
        int beg = ofs[node], end = ofs[node + 1];
        float acc[8];
        #pragma unroll
        for (int i = 0; i < 8; ++i) acc[i] = 0.f;

        for (int j = beg; j < end; j += 64) {
            int m = end - j;
            if (m > 64) m = 64;
            int idx = (l < m) ? esrc[j + l] : 0;
            for (int t = 0; 4 * t < m; t += 4) {
                int e0 = 4 * t + q, e1 = e0 + 4, e2 = e0 + 8, e3 = e0 + 12;
                int s0 = __shfl(idx, e0 & 63);
                int s1 = __shfl(idx, e1 & 63);
                int s2 = __shfl(idx, e2 & 63);
                int s3 = __shfl(idx, e3 & 63);
                uint4 v0 = *(const uint4*)(xs + (size_t)s0 * 128 + li * 8);
                uint4 v1 = *(const uint4*)(xs + (size_t)s1 * 128 + li * 8);
                uint4 v2 = *(const uint4*)(xs + (size_t)s2 * 128 + li * 8);
                uint4 v3 = *(const uint4*)(xs + (size_t)s3 * 128 + li * 8);
                if (e0 < m) { ACC8(v0) }
                if (e1 < m) { ACC8(v1) }
                if (e2 < m) { ACC8(v2) }
                if (e3 < m) { ACC8(v3) }
            }
        }
        #pragma unroll
        for (int i = 0; i < 8; ++i) acc[i] += __shfl(acc[i], l ^ 16);
        #pragma unroll
        for (int i = 0; i < 8; ++i) acc[i] += __shfl(acc[i], l ^ 32);

        if (l < 16) {
            float sc = rsqrtf(fmaxf((float)(end - beg), 1.0f));
            *(uint4*)&As[wv][nn][li * 8] =
                make_uint4(pk2(acc[0] * sc, acc[1] * sc), pk2(acc[2] * sc, acc[3] * sc),
                           pk2(acc[4] * sc, acc[5] * sc), pk2(acc[6] * sc, acc[7] * sc));
        }
    }

    // ---- MFMA phase (per-wave, no barrier needed: own LDS slice) ----
    bf16x8 af[4];
    #pragma unroll
    for (int kc = 0; kc < 4; ++kc)
        af[kc] = *(const bf16x8*)&As[wv][li][kc * 32 + q * 8];

    f32x4 acc2[8];
    #pragma unroll
    for (int nt = 0; nt < 8; ++nt) acc2[nt] = (f32x4){0.f, 0.f, 0.f, 0.f};

    #pragma unroll
    for (int kc = 0; kc < 4; ++kc) {
        #pragma unroll
        for (int nt = 0; nt < 8; ++nt) {
            bf16x8 bfr = *(const bf16x8*)(Wf + ((size_t)(nt * 4 + kc) * 64 + l) * 8);
            acc2[nt] = __builtin_amdgcn_mfma_f32_16x16x32_bf16(af[kc], bfr, acc2[nt], 0, 0, 0);
        }
    }

    // C/D: lane l, reg j -> row base+q*4+j, col nt*16+li
    int orow = base + q * 4;
    #pragma unroll
    for (int nt = 0; nt < 8; ++nt) {
        float bv = bias[nt * 16 + li];
        #pragma unroll
        for (int j = 0; j < 4; ++j) {
            float x = fmaxf(acc2[nt][j] + bv, 0.0f);
            h[(size_t)(orow + j) * 128 + nt * 16 + li] = (ushort_t)f2b(x);
        }
    }
}

// ---------------- MFMA GEMM2: ys_bf16[N,64] = h[N,128] @ Wf2, *rsqrt(dego[row]) ----------------

__global__ __launch_bounds__(256) void mgemm2_k(const ushort_t* __restrict__ A,
                                                const ushort_t* __restrict__ Wf,
                                                const int* __restrict__ dego,
                                                ushort_t* __restrict__ out) {
    constexpr int NT = 4;  // 64/16
    int wv = threadIdx.x >> 6;
    int l = threadIdx.x & 63;
    int r0 = (blockIdx.x * 4 + wv) * 16;
    if (r0 >= N_NODES) return;

    const ushort_t* ap = A + (size_t)(r0 + (l & 15)) * 128 + (l >> 4) * 8;
    bf16x8 af[4];
    #pragma unroll
    for (int kc = 0; kc < 4; ++kc) af[kc] = *(const bf16x8*)(ap + kc * 32);

    f32x4 acc[NT];
    #pragma unroll
    for (int nt = 0; nt < NT; ++nt) acc[nt] = (f32x4){0.f, 0.f, 0.f, 0.f};

    #pragma unroll
    for (int kc = 0; kc < 4; ++kc) {
        #pragma unroll
        for (int nt = 0; nt < NT; ++nt) {
            bf16x8 bfr = *(const bf16x8*)(Wf + ((size_t)(nt * 4 + kc) * 64 + l) * 8);
            acc[nt] = __builtin_amdgcn_mfma_f32_16x16x32_bf16(af[kc], bfr, acc[nt], 0, 0, 0);
        }
    }

    int orow = r0 + (l >> 4) * 4;
    int col = l & 15;
    float os[4];
    #pragma unroll
    for (int j = 0; j < 4; ++j) os[j] = rsqrtf(fmaxf((float)dego[orow + j], 1.0f));
    #pragma unroll
    for (int nt = 0; nt < NT; ++nt) {
        #pragma unroll
        for (int j = 0; j < 4; ++j) {
            out[(size_t)(orow + j) * 64 + nt * 16 + col] = (ushort_t)f2b(acc[nt][j] * os[j]);
        }
    }
}

// ---------------- agg over 64-dim bf16 rows + bias -> f32 out ----------------
// 8 lanes x uint4 (16B) per 128B row; 8 edges concurrent, 2x unrolled.

__global__ __launch_bounds__(256) void agg64_k(const ushort_t* __restrict__ ys,
                                               const int* __restrict__ esrc,
                                               const int* __restrict__ ofs,
                                               const float* __restrict__ b2,
                                               float* __restrict__ out) {
    int wid = (blockIdx.x * 256 + threadIdx.x) >> 6;
    int lane = threadIdx.x & 63;
    int og = lane >> 3, li = lane & 7;
    int beg = ofs[wid], end = ofs[wid + 1];
    float acc[8];
    #pragma unroll
    for (int i = 0; i < 8; ++i) acc[i] = 0.f;

    for (int j = beg; j < end; j += 64) {
        int m = end - j;
        if (m > 64) m = 64;
        int idx = (lane < m) ? esrc[j + lane] : 0;
        for (int t = 0; 8 * t < m; t += 2) {
            int e0 = 8 * t + og, e1 = e0 + 8;
            int s0 = __shfl(idx, e0 & 63);
            int s1 = __shfl(idx, e1 & 63);
            uint4 v0 = *(const uint4*)(ys + (size_t)s0 * 64 + li * 8);
            uint4 v1 = *(const uint4*)(ys + (size_t)s1 * 64 + li * 8);
            if (e0 < m) { ACC8(v0) }
            if (e1 < m) { ACC8(v1) }
        }
    }
    #pragma unroll
    for (int i = 0; i < 8; ++i) acc[i] += __shfl(acc[i], lane ^ 8);
    #pragma unroll
    for (int i = 0; i < 8; ++i) acc[i] += __shfl(acc[i], lane ^ 16);
    #pragma unroll
    for (int i = 0; i < 8; ++i) acc[i] += __shfl(acc[i], lane ^ 32);

    if (lane < 8) {
        float sc = rsqrtf(fmaxf((float)(end - beg), 1.0f));
        float4 ba = *(const float4*)(b2 + li * 8);
        float4 bb = *(const float4*)(b2 + li * 8 + 4);
        float* op = out + (size_t)wid * 64 + li * 8;
        *(float4*)op = make_float4(acc[0] * sc + ba.x, acc[1] * sc + ba.y,
                                   acc[2] * sc + ba.z, acc[3] * sc + ba.w);
        *(float4*)(op + 4) = make_float4(acc[4] * sc + bb.x, acc[5] * sc + bb.y,
                                         acc[6] * sc + bb.z, acc[7] * sc + bb.w);
    }
}

extern "C" void kernel_launch(void* const* d_in, const int* in_sizes, int n_in,
                              void* d_out, int out_size, void* d_ws, size_t ws_size,
                              hipStream_t stream) {
    const float* in_feat = (const float*)d_in[0];
    const float* W1 = (const float*)d_in[1];
    const float* b1 = (const float*)d_in[2];
    const float* W2 = (const float*)d_in[3];
    const float* b2 = (const float*)d_in[4];
    const int* src = (const int*)d_in[5];
    const int* dst = (const int*)d_in[6];
    float* out = (float*)d_out;

    // workspace layout (16B-aligned slots)
    char* w = (char*)d_ws;
    int* dego = (int*)w;       w += (size_t)N_NODES * 4;
    int* ofs = (int*)w;        w += (size_t)(N_NODES + 4) * 4;
    int* hist = (int*)w;       w += (size_t)CELLS * 4;
    int* histOfs = (int*)w;    w += (size_t)CELLS * 4;
    int* partial = (int*)w;    w += 512 * 4;
    int* partofs = (int*)w;    w += 512 * 4;
    uint_t* ebuf = (uint_t*)w; w += (size_t)N_EDGES * 4;
    int* esrc = (int*)w;       w += (size_t)N_EDGES * 4;
    ushort_t* Wf1 = (ushort_t*)w; w += (size_t)HID_DIM * 16 * 16;  // 32 KB frag-packed W1
    ushort_t* Wf2 = (ushort_t*)w; w += (size_t)OUT_DIM * 16 * 16;  // 16 KB frag-packed W2
    ushort_t* bufA = (ushort_t*)w; w += (size_t)N_NODES * HID_DIM * 2;  // xs -> ys
    ushort_t* bufB = (ushort_t*)w; w += (size_t)N_NODES * HID_DIM * 2;  // h

    // out-degrees + dst-bucket histogram (single pass over edges)
    hipMemsetAsync(dego, 0, (size_t)N_NODES * 4, stream);
    histdeg_k<<<GRIDB, 256, 0, stream>>>(src, dst, dego, hist);

    // CSR by dst via bucketed counting sort (LDS atomics only)
    scan_part_k<<<SNPART, 256, 0, stream>>>(hist, partial, CELLS);
    scan_top_k<<<1, 512, 0, stream>>>(partial, partofs, SNPART);
    scan_final_k<<<SNPART, 256, 0, stream>>>(hist, partofs, histOfs, CELLS);
    scat_k<<<GRIDB, 256, 0, stream>>>(src, dst, histOfs, ebuf);
    fin_k<<<NB, 256, 0, stream>>>(ebuf, histOfs, ofs, esrc);

    // pack W fragments (tiny)
    wprep_k<<<(HID_DIM * 16 + 255) / 256, 256, 0, stream>>>(W1, Wf1, HID_DIM);
    wprep_k<<<(OUT_DIM * 16 + 255) / 256, 256, 0, stream>>>(W2, Wf2, OUT_DIM);

    // layer 1: xs = bf16(x*rsqrt(dego)); h = relu((invi*Agg(xs))@W1 + b1)  [fused]
    prep_k<<<N_NODES * 16 / 256, 256, 0, stream>>>(in_feat, dego, bufA);
    aggmm128_k<<<(N_NODES + 63) / 64, 256, 0, stream>>>(bufA, esrc, ofs, Wf1, b1, bufB);

    // layer 2: ys = bf16((h@W2)*rsqrt(dego)); out = invi*Agg(ys) + b2
    mgemm2_k<<<(N_NODES / 16 + 3) / 4, 256, 0, stream>>>(bufB, Wf2, dego, bufA);
    agg64_k<<<N_NODES / 4, 256, 0, stream>>>(bufA, esrc, ofs, b2, out);
}